// Round 5
// baseline (19059.683 us; speedup 1.0000x reference)
//
#include <hip/hip_runtime.h>
#include <math.h>

#define IN_DIM 1024
#define MEM 1024
#define NNODE 2048
#define GX_COLS 5120   // [i|o|f|z|u] blocks of 1024

// ---- scan configuration ----
#define NWG 128          // persistent workgroups (<= 256 CUs -> co-resident)
#define WGT 768          // 12 waves: 8 compute + 2 h-stagers + 2 v-stagers
#define DPW 8            // dims per WG  (MEM / NWG)
#define PUBI (NWG * 16)  // ints per parity in a pub buffer (128 WGs x 8 pairs)

__device__ __forceinline__ float fsig(float x) {
  return __builtin_amdgcn_rcpf(1.f + __expf(-x));
}
__device__ __forceinline__ float ftanh(float x) {
  // tanh(x) = 1 - 2/(exp(2x)+1); saturates correctly for |x| large
  return 1.f - 2.f * __builtin_amdgcn_rcpf(1.f + __expf(2.f * x));
}

// ---- self-validating 8B packets: (float value, int step-tag) ----
// DEVICE scope = sc1 only (served by the die-level Infinity Cache).
// sc0+sc1 is SYSTEM scope and goes to DRAM — ~3x the latency (round-4 bug).
__device__ __forceinline__ void store_pair(int* p, float v, int tg) {
  int2 d; d.x = __float_as_int(v); d.y = tg;
  asm volatile("global_store_dwordx2 %0, %1, off sc1"
               :: "v"(p), "v"(d) : "memory");
}
// poll one producer's 8 pairs (64B) until all tags match, return the values
__device__ __forceinline__ void poll_pairs(const int* p, int tg,
                                           float4& lo, float4& hi) {
  int4 a, b, c, d;
  do {
    asm volatile(
        "global_load_dwordx4 %0, %4, off sc1\n\t"
        "global_load_dwordx4 %1, %4, off offset:16 sc1\n\t"
        "global_load_dwordx4 %2, %4, off offset:32 sc1\n\t"
        "global_load_dwordx4 %3, %4, off offset:48 sc1\n\t"
        "s_waitcnt vmcnt(0)"
        : "=v"(a), "=v"(b), "=v"(c), "=v"(d)
        : "v"(p) : "memory");
  } while (((a.y ^ tg) | (a.w ^ tg) | (b.y ^ tg) | (b.w ^ tg) |
            (c.y ^ tg) | (c.w ^ tg) | (d.y ^ tg) | (d.w ^ tg)) != 0);
  lo = make_float4(__int_as_float(a.x), __int_as_float(a.z),
                   __int_as_float(b.x), __int_as_float(b.z));
  hi = make_float4(__int_as_float(c.x), __int_as_float(c.z),
                   __int_as_float(d.x), __int_as_float(d.z));
}

// ---------------- init: seed the pub buffers ----------------
// h parity0 = (0.0, tag 0) [the step-0 input]; h parity1 and all v = tag -1.
// Plain stores are fine: dispatch-end writes back L2, and the scan kernel
// itself never caches the pub region in L2 (all accesses are sc1).
__global__ void init_ctrl(int* h_pub, int* v_pub) {
  int t = threadIdx.x;
  for (int i = t; i < PUBI / 2; i += blockDim.x) {
    h_pub[2 * i + 0] = 0;            // value 0.0f
    h_pub[2 * i + 1] = 0;            // tag 0   (parity 0)
    h_pub[PUBI + 2 * i + 0] = 0;
    h_pub[PUBI + 2 * i + 1] = -1;    // parity 1 invalid
  }
  for (int i = t; i < PUBI; i += blockDim.x) {
    v_pub[2 * i + 0] = 0;
    v_pub[2 * i + 1] = -1;           // both parities invalid
  }
}

// ---------------- Gx = inputs @ Wx + bx ----------------
// A: 2048x1024, B: 1024x5120, C: 2048x5120. 128x128 tile, 256 thr, 8x8/thr.
__global__ __launch_bounds__(256) void gemm_gx(
    const float* __restrict__ A, const float* __restrict__ B,
    const float* __restrict__ bias, float* __restrict__ C) {
  __shared__ float As[8][128];
  __shared__ float Bs[8][132];
  const int tid = threadIdx.x;
  const int bm = blockIdx.y * 128;
  const int bn = blockIdx.x * 128;
  const int tx = tid & 15;
  const int ty = tid >> 4;
  const int am = tid >> 1;
  const int ak = (tid & 1) * 4;
  const int bk = tid >> 5;
  const int bn4 = (tid & 31) * 4;

  float acc[8][8] = {};
  for (int k0 = 0; k0 < IN_DIM; k0 += 8) {
    float4 av = *(const float4*)&A[(size_t)(bm + am) * IN_DIM + k0 + ak];
    float4 bv = *(const float4*)&B[(size_t)(k0 + bk) * GX_COLS + bn + bn4];
    __syncthreads();
    As[ak + 0][am] = av.x;
    As[ak + 1][am] = av.y;
    As[ak + 2][am] = av.z;
    As[ak + 3][am] = av.w;
    *(float4*)&Bs[bk][bn4] = bv;
    __syncthreads();
#pragma unroll
    for (int kk = 0; kk < 8; ++kk) {
      float4 a0 = *(const float4*)&As[kk][ty * 4];
      float4 a1 = *(const float4*)&As[kk][64 + ty * 4];
      float4 b0 = *(const float4*)&Bs[kk][tx * 4];
      float4 b1 = *(const float4*)&Bs[kk][64 + tx * 4];
      float a[8] = {a0.x, a0.y, a0.z, a0.w, a1.x, a1.y, a1.z, a1.w};
      float b[8] = {b0.x, b0.y, b0.z, b0.w, b1.x, b1.y, b1.z, b1.w};
#pragma unroll
      for (int i = 0; i < 8; ++i)
#pragma unroll
        for (int j = 0; j < 8; ++j) acc[i][j] += a[i] * b[j];
    }
  }
  float4 bias0 = *(const float4*)&bias[bn + tx * 4];
  float4 bias1 = *(const float4*)&bias[bn + 64 + tx * 4];
#pragma unroll
  for (int i = 0; i < 8; ++i) {
    int row = bm + ((i < 4) ? (ty * 4 + i) : (64 + ty * 4 + (i - 4)));
    float4 c0 = {acc[i][0] + bias0.x, acc[i][1] + bias0.y,
                 acc[i][2] + bias0.z, acc[i][3] + bias0.w};
    float4 c1 = {acc[i][4] + bias1.x, acc[i][5] + bias1.y,
                 acc[i][6] + bias1.z, acc[i][7] + bias1.w};
    *(float4*)&C[(size_t)row * GX_COLS + bn + tx * 4] = c0;
    *(float4*)&C[(size_t)row * GX_COLS + bn + 64 + tx * 4] = c1;
  }
}

// ---------------- persistent chain scan ----------------
// Waves 0-7 compute (wave w owns dim j = wg*8+w, in-wave K=1024 reduction).
// Waves 8-9: dedicated h-stagers (poll h_{t+1} DURING round B compute).
// Waves 10-11: dedicated v-stagers (poll v_t DURING round A compute).
// Leaders publish their dim's (value,tag) packet directly (no share hop).
__global__ __launch_bounds__(WGT) void scan_kernel(
    const float* __restrict__ Wh, const float* __restrict__ bh,
    const float* __restrict__ Wum, const float* __restrict__ bum,
    const float* __restrict__ pic, const float* __restrict__ pfc,
    const float* __restrict__ poc, const float* __restrict__ pzc,
    const float* __restrict__ Gx,
    int* h_pub, int* v_pub,
    float* __restrict__ out) {
  const int wg = blockIdx.x;
  const int tid = threadIdx.x;
  const int w = tid >> 6;    // wave id: 0-7 compute, 8-9 h-stage, 10-11 v-stage
  const int ln = tid & 63;
  const int j = wg * DPW + w;          // valid for w<8
  const bool leader = (ln == 0) && (w < 8);

  __shared__ float h_lds[MEM];
  __shared__ float v_lds[MEM];

  // register-resident weight slices (compute waves only): k = ln*4 + m*256 + e
  float wi[16], wo[16], wf[16], wz[16], wu[16];
  if (w < 8) {
#pragma unroll
    for (int m = 0; m < 4; ++m)
#pragma unroll
      for (int e = 0; e < 4; ++e) {
        int k = ln * 4 + m * 256 + e;
        wi[m * 4 + e] = Wh[(size_t)k * 4096 + 0 * MEM + j];
        wo[m * 4 + e] = Wh[(size_t)k * 4096 + 1 * MEM + j];
        wf[m * 4 + e] = Wh[(size_t)k * 4096 + 2 * MEM + j];
        wz[m * 4 + e] = Wh[(size_t)k * 4096 + 3 * MEM + j];
        wu[m * 4 + e] = Wum[(size_t)k * MEM + j];
      }
  }

  float b_i = 0, b_o = 0, b_f = 0, b_z = 0, b_u = 0;
  float p_i = 0, p_f = 0, p_o = 0, p_z = 0;
  if (leader) {
    b_i = bh[0 * MEM + j]; b_o = bh[1 * MEM + j];
    b_f = bh[2 * MEM + j]; b_z = bh[3 * MEM + j];
    b_u = bum[j];
    p_i = pic[j]; p_f = pfc[j]; p_o = poc[j]; p_z = pzc[j];
  }

  float c = 0.f, hmax = -1e30f;
  float i_keep = 0, f_keep = 0, oh_keep = 0, gux_keep = 0;

  for (int t = 0; t < NNODE; ++t) {
    // ---- h-stagers: poll+stage h_t (tag t). For t>0 this overlapped with
    // the previous iteration's round B (they passed barrier B early). ----
    if (w == 8 || w == 9) {
      const int idx = (w - 8) * 64 + ln;   // producer WG 0..127
      float4 lo, hi;
      poll_pairs(h_pub + (t & 1) * PUBI + idx * 16, t, lo, hi);
      *(float4*)&h_lds[idx * 8] = lo;
      *(float4*)&h_lds[idx * 8 + 4] = hi;
    }
    __syncthreads();                       // BARRIER A: h_lds ready

    if (w < 8) {
      // Gx prefetch (plain cached loads; latency hidden under the dot)
      float gix = 0, gox = 0, gfx = 0, gzx = 0, gux = 0;
      if (ln == 0) {
        const float* gx = Gx + (size_t)t * GX_COLS;
        gix = gx[j]; gox = gx[MEM + j]; gfx = gx[2 * MEM + j];
        gzx = gx[3 * MEM + j]; gux = gx[4 * MEM + j];
      }
      float hreg[16];
#pragma unroll
      for (int m = 0; m < 4; ++m)
        *(float4*)&hreg[m * 4] = *(const float4*)&h_lds[m * 256 + ln * 4];

      // ---- early-z: z-gate dot + reduce + publish v FIRST ----
      float sz = 0;
#pragma unroll
      for (int e = 0; e < 16; ++e) sz += hreg[e] * wz[e];
#pragma unroll
      for (int off = 32; off >= 1; off >>= 1) sz += __shfl_down(sz, off);
      if (ln == 0) {
        float zv = fsig(gzx + sz + b_z + p_z * c);
        float vv = zv * ftanh(c);
        store_pair(v_pub + (t & 1) * PUBI + (wg * 8 + w) * 2, vv, t + 1);
      }
      // ---- remaining gates ----
      float si = 0, so = 0, sf = 0;
#pragma unroll
      for (int e = 0; e < 16; ++e) {
        si += hreg[e] * wi[e]; so += hreg[e] * wo[e]; sf += hreg[e] * wf[e];
      }
#pragma unroll
      for (int off = 32; off >= 1; off >>= 1) {
        si += __shfl_down(si, off); so += __shfl_down(so, off);
        sf += __shfl_down(sf, off);
      }
      if (ln == 0) {
        i_keep = fsig(gix + si + b_i + p_i * c);
        f_keep = fsig(gfx + sf + b_f + p_f * c);
        oh_keep = gox + so + b_o;
        gux_keep = gux;
      }
    } else if (w >= 10) {
      // ---- v-stagers: poll+stage v_t (tag t+1), overlapping round A ----
      const int idx = (w - 10) * 64 + ln;
      float4 lo, hi;
      poll_pairs(v_pub + (t & 1) * PUBI + idx * 16, t + 1, lo, hi);
      *(float4*)&v_lds[idx * 8] = lo;
      *(float4*)&v_lds[idx * 8 + 4] = hi;
    }
    __syncthreads();                       // BARRIER B: v_lds ready

    if (w < 8) {
      float sm = 0;
#pragma unroll
      for (int m = 0; m < 4; ++m) {
        float4 vv4 = *(const float4*)&v_lds[m * 256 + ln * 4];
        const float* vv = (const float*)&vv4;
#pragma unroll
        for (int e = 0; e < 4; ++e) sm += vv[e] * wu[m * 4 + e];
      }
#pragma unroll
      for (int off = 32; off >= 1; off >>= 1) sm += __shfl_down(sm, off);
      if (ln == 0) {
        float uv = ftanh(gux_keep + sm + b_u);
        float cn = i_keep * uv + f_keep * c;
        float ov = fsig(oh_keep + p_o * cn);
        float hn = ov * ftanh(cn);
        c = cn;
        store_pair(h_pub + ((t + 1) & 1) * PUBI + (wg * 8 + w) * 2, hn, t + 1);
        hmax = fmaxf(hmax, hn);
      }
    }
    // h-stagers fall through to the next iteration's poll here, overlapping
    // the compute waves' round B above.
  }

  if (leader) out[j] = hmax;
}

extern "C" void kernel_launch(void* const* d_in, const int* in_sizes, int n_in,
                              void* d_out, int out_size, void* d_ws, size_t ws_size,
                              hipStream_t stream) {
  const float* inputs = (const float*)d_in[0];
  const float* Wx  = (const float*)d_in[1];
  const float* bx  = (const float*)d_in[2];
  const float* Wh  = (const float*)d_in[3];
  const float* bh  = (const float*)d_in[4];
  const float* Wum = (const float*)d_in[5];
  const float* bum = (const float*)d_in[6];
  const float* pic = (const float*)d_in[7];
  const float* pfc = (const float*)d_in[8];
  const float* poc = (const float*)d_in[9];
  const float* pzc = (const float*)d_in[10];
  float* out = (float*)d_out;

  // ws: Gx (2048*5120 f32) | h_pub (2*PUBI ints) | v_pub (2*PUBI ints)
  float* Gx = (float*)d_ws;
  int* h_pub = (int*)(Gx + (size_t)NNODE * GX_COLS);
  int* v_pub = h_pub + 2 * PUBI;

  init_ctrl<<<1, 256, 0, stream>>>(h_pub, v_pub);
  gemm_gx<<<dim3(GX_COLS / 128, NNODE / 128), 256, 0, stream>>>(inputs, Wx, bx, Gx);
  scan_kernel<<<NWG, WGT, 0, stream>>>(Wh, bh, Wum, bum, pic, pfc, poc, pzc,
                                       Gx, h_pub, v_pub, out);
}

// Round 6
// 9545.718 us; speedup vs baseline: 1.9967x; 1.9967x over previous
//
#include <hip/hip_runtime.h>
#include <math.h>

#define IN_DIM 1024
#define MEM 1024
#define NNODE 2048
#define GX_COLS 5120   // [i|o|f|z|u] blocks of 1024

// ---- scan configuration ----
#define NWG 128          // persistent workgroups (<= 256 CUs -> co-resident)
#define WGT 512          // 8 waves; wave w owns dim j = wg*8+w
#define DPW 8            // dims per WG  (MEM / NWG)
#define PUBI (NWG * 16)  // ints per parity in a pub buffer (128 WGs x 8 pairs)

__device__ __forceinline__ float fsig(float x) {
  return __builtin_amdgcn_rcpf(1.f + __expf(-x));
}
__device__ __forceinline__ float ftanh(float x) {
  // tanh(x) = 1 - 2/(exp(2x)+1); saturates correctly for |x| large
  return 1.f - 2.f * __builtin_amdgcn_rcpf(1.f + __expf(2.f * x));
}

// ---- self-validating 8B packets: (float value, int step-tag) ----
// sc0 sc1 scope proven in round 4 (9.1 ms); round 5's sc1-only regressed.
__device__ __forceinline__ void store_pair(int* p, float v, int tg) {
  int2 d; d.x = __float_as_int(v); d.y = tg;
  asm volatile("global_store_dwordx2 %0, %1, off sc0 sc1"
               :: "v"(p), "v"(d) : "memory");
}
// poll one producer's 8 pairs (64B) until all tags match; s_sleep backoff
// after each failed check caps the request storm on the hot LLC lines.
__device__ __forceinline__ void poll_pairs(const int* p, int tg,
                                           float4& lo, float4& hi) {
  int4 a, b, c, d;
  for (;;) {
    asm volatile(
        "global_load_dwordx4 %0, %4, off sc0 sc1\n\t"
        "global_load_dwordx4 %1, %4, off offset:16 sc0 sc1\n\t"
        "global_load_dwordx4 %2, %4, off offset:32 sc0 sc1\n\t"
        "global_load_dwordx4 %3, %4, off offset:48 sc0 sc1\n\t"
        "s_waitcnt vmcnt(0)"
        : "=v"(a), "=v"(b), "=v"(c), "=v"(d)
        : "v"(p) : "memory");
    if ((((a.y ^ tg) | (a.w ^ tg) | (b.y ^ tg) | (b.w ^ tg) |
          (c.y ^ tg) | (c.w ^ tg) | (d.y ^ tg) | (d.w ^ tg))) == 0) break;
    __builtin_amdgcn_s_sleep(1);
  }
  lo = make_float4(__int_as_float(a.x), __int_as_float(a.z),
                   __int_as_float(b.x), __int_as_float(b.z));
  hi = make_float4(__int_as_float(c.x), __int_as_float(c.z),
                   __int_as_float(d.x), __int_as_float(d.z));
}

// ---------------- init: seed the pub buffers ----------------
// h parity0 = (0.0, tag 0) [the step-0 input]; h parity1 and all v = tag -1.
__global__ void init_ctrl(int* h_pub, int* v_pub) {
  int t = threadIdx.x;
  for (int i = t; i < PUBI / 2; i += blockDim.x) {
    h_pub[2 * i + 0] = 0;            // value 0.0f
    h_pub[2 * i + 1] = 0;            // tag 0   (parity 0)
    h_pub[PUBI + 2 * i + 0] = 0;
    h_pub[PUBI + 2 * i + 1] = -1;    // parity 1 invalid
  }
  for (int i = t; i < PUBI; i += blockDim.x) {
    v_pub[2 * i + 0] = 0;
    v_pub[2 * i + 1] = -1;           // both parities invalid
  }
}

// ---------------- Gx = inputs @ Wx + bx ----------------
// A: 2048x1024, B: 1024x5120, C: 2048x5120. 128x128 tile, 256 thr, 8x8/thr.
__global__ __launch_bounds__(256) void gemm_gx(
    const float* __restrict__ A, const float* __restrict__ B,
    const float* __restrict__ bias, float* __restrict__ C) {
  __shared__ float As[8][128];
  __shared__ float Bs[8][132];
  const int tid = threadIdx.x;
  const int bm = blockIdx.y * 128;
  const int bn = blockIdx.x * 128;
  const int tx = tid & 15;
  const int ty = tid >> 4;
  const int am = tid >> 1;
  const int ak = (tid & 1) * 4;
  const int bk = tid >> 5;
  const int bn4 = (tid & 31) * 4;

  float acc[8][8] = {};
  for (int k0 = 0; k0 < IN_DIM; k0 += 8) {
    float4 av = *(const float4*)&A[(size_t)(bm + am) * IN_DIM + k0 + ak];
    float4 bv = *(const float4*)&B[(size_t)(k0 + bk) * GX_COLS + bn + bn4];
    __syncthreads();
    As[ak + 0][am] = av.x;
    As[ak + 1][am] = av.y;
    As[ak + 2][am] = av.z;
    As[ak + 3][am] = av.w;
    *(float4*)&Bs[bk][bn4] = bv;
    __syncthreads();
#pragma unroll
    for (int kk = 0; kk < 8; ++kk) {
      float4 a0 = *(const float4*)&As[kk][ty * 4];
      float4 a1 = *(const float4*)&As[kk][64 + ty * 4];
      float4 b0 = *(const float4*)&Bs[kk][tx * 4];
      float4 b1 = *(const float4*)&Bs[kk][64 + tx * 4];
      float a[8] = {a0.x, a0.y, a0.z, a0.w, a1.x, a1.y, a1.z, a1.w};
      float b[8] = {b0.x, b0.y, b0.z, b0.w, b1.x, b1.y, b1.z, b1.w};
#pragma unroll
      for (int i = 0; i < 8; ++i)
#pragma unroll
        for (int j = 0; j < 8; ++j) acc[i][j] += a[i] * b[j];
    }
  }
  float4 bias0 = *(const float4*)&bias[bn + tx * 4];
  float4 bias1 = *(const float4*)&bias[bn + 64 + tx * 4];
#pragma unroll
  for (int i = 0; i < 8; ++i) {
    int row = bm + ((i < 4) ? (ty * 4 + i) : (64 + ty * 4 + (i - 4)));
    float4 c0 = {acc[i][0] + bias0.x, acc[i][1] + bias0.y,
                 acc[i][2] + bias0.z, acc[i][3] + bias0.w};
    float4 c1 = {acc[i][4] + bias1.x, acc[i][5] + bias1.y,
                 acc[i][6] + bias1.z, acc[i][7] + bias1.w};
    *(float4*)&C[(size_t)row * GX_COLS + bn + tx * 4] = c0;
    *(float4*)&C[(size_t)row * GX_COLS + bn + 64 + tx * 4] = c1;
  }
}

// ---------------- persistent chain scan ----------------
// Wave w owns dim j = wg*8+w (in-wave K=1024 reduction, k = ln*4+m*256+e).
// Inline staging windows (round-4 style): waves 1-2 poll h at loop top,
// waves 3-4 poll v after their gate dots. Direct per-wave publish: each
// wave's lane 0 stores its dim's (value,tag) packet the moment it's ready
// (early-z for v). Only 2 barriers per step.
__global__ __launch_bounds__(WGT) void scan_kernel(
    const float* __restrict__ Wh, const float* __restrict__ bh,
    const float* __restrict__ Wum, const float* __restrict__ bum,
    const float* __restrict__ pic, const float* __restrict__ pfc,
    const float* __restrict__ poc, const float* __restrict__ pzc,
    const float* __restrict__ Gx,
    int* h_pub, int* v_pub,
    float* __restrict__ out) {
  const int wg = blockIdx.x;
  const int tid = threadIdx.x;
  const int w = tid >> 6;    // wave id == owned local dim
  const int ln = tid & 63;
  const int j = wg * DPW + w;

  __shared__ float h_lds[MEM];
  __shared__ float v_lds[MEM];

  // register-resident weight slices: k = ln*4 + m*256 + e
  float wi[16], wo[16], wf[16], wz[16], wu[16];
#pragma unroll
  for (int m = 0; m < 4; ++m)
#pragma unroll
    for (int e = 0; e < 4; ++e) {
      int k = ln * 4 + m * 256 + e;
      wi[m * 4 + e] = Wh[(size_t)k * 4096 + 0 * MEM + j];
      wo[m * 4 + e] = Wh[(size_t)k * 4096 + 1 * MEM + j];
      wf[m * 4 + e] = Wh[(size_t)k * 4096 + 2 * MEM + j];
      wz[m * 4 + e] = Wh[(size_t)k * 4096 + 3 * MEM + j];
      wu[m * 4 + e] = Wum[(size_t)k * MEM + j];
    }

  float b_i = 0, b_o = 0, b_f = 0, b_z = 0, b_u = 0;
  float p_i = 0, p_f = 0, p_o = 0, p_z = 0;
  if (ln == 0) {
    b_i = bh[0 * MEM + j]; b_o = bh[1 * MEM + j];
    b_f = bh[2 * MEM + j]; b_z = bh[3 * MEM + j];
    b_u = bum[j];
    p_i = pic[j]; p_f = pfc[j]; p_o = poc[j]; p_z = pzc[j];
  }

  float c = 0.f, hmax = -1e30f;
  float i_keep = 0, f_keep = 0, oh_keep = 0, gux_keep = 0;

  for (int t = 0; t < NNODE; ++t) {
    // Gx prefetch: issued first so it overlaps the h poll/barrier
    float gix = 0, gox = 0, gfx = 0, gzx = 0, gux = 0;
    if (ln == 0) {
      const float* gx = Gx + (size_t)t * GX_COLS;
      gix = gx[j]; gox = gx[MEM + j]; gfx = gx[2 * MEM + j];
      gzx = gx[3 * MEM + j]; gux = gx[4 * MEM + j];
    }

    // ---- staging window: waves 1-2 poll+stage h_{t-1} (tag t) ----
    if (w == 1 || w == 2) {
      const int idx = (w - 1) * 64 + ln;   // producer WG 0..127
      float4 lo, hi;
      poll_pairs(h_pub + (t & 1) * PUBI + idx * 16, t, lo, hi);
      *(float4*)&h_lds[idx * 8] = lo;
      *(float4*)&h_lds[idx * 8 + 4] = hi;
    }
    __syncthreads();                       // BARRIER A: h_lds ready

    float hreg[16];
#pragma unroll
    for (int m = 0; m < 4; ++m)
      *(float4*)&hreg[m * 4] = *(const float4*)&h_lds[m * 256 + ln * 4];

    // ---- early-z: z dot + reduce + direct publish of v ----
    float sz = 0;
#pragma unroll
    for (int e = 0; e < 16; ++e) sz += hreg[e] * wz[e];
#pragma unroll
    for (int off = 32; off >= 1; off >>= 1) sz += __shfl_down(sz, off);
    if (ln == 0) {
      float zv = fsig(gzx + sz + b_z + p_z * c);
      float vv = zv * ftanh(c);
      store_pair(v_pub + (t & 1) * PUBI + j * 2, vv, t + 1);
    }

    // ---- remaining gate dots (overlap v propagation) ----
    float si = 0, so = 0, sf = 0;
#pragma unroll
    for (int e = 0; e < 16; ++e) {
      si += hreg[e] * wi[e]; so += hreg[e] * wo[e]; sf += hreg[e] * wf[e];
    }
#pragma unroll
    for (int off = 32; off >= 1; off >>= 1) {
      si += __shfl_down(si, off); so += __shfl_down(so, off);
      sf += __shfl_down(sf, off);
    }
    if (ln == 0) {
      i_keep = fsig(gix + si + b_i + p_i * c);
      f_keep = fsig(gfx + sf + b_f + p_f * c);
      oh_keep = gox + so + b_o;
      gux_keep = gux;
    }

    // ---- staging window: waves 3-4 poll+stage v_t (tag t+1) ----
    if (w == 3 || w == 4) {
      const int idx = (w - 3) * 64 + ln;
      float4 lo, hi;
      poll_pairs(v_pub + (t & 1) * PUBI + idx * 16, t + 1, lo, hi);
      *(float4*)&v_lds[idx * 8] = lo;
      *(float4*)&v_lds[idx * 8 + 4] = hi;
    }
    __syncthreads();                       // BARRIER B: v_lds ready

    float sm = 0;
#pragma unroll
    for (int m = 0; m < 4; ++m) {
      float4 vv4 = *(const float4*)&v_lds[m * 256 + ln * 4];
      const float* vv = (const float*)&vv4;
#pragma unroll
      for (int e = 0; e < 4; ++e) sm += vv[e] * wu[m * 4 + e];
    }
#pragma unroll
    for (int off = 32; off >= 1; off >>= 1) sm += __shfl_down(sm, off);
    if (ln == 0) {
      float uv = ftanh(gux_keep + sm + b_u);
      float cn = i_keep * uv + f_keep * c;
      float ov = fsig(oh_keep + p_o * cn);
      float hn = ov * ftanh(cn);
      c = cn;
      store_pair(h_pub + ((t + 1) & 1) * PUBI + j * 2, hn, t + 1);
      hmax = fmaxf(hmax, hn);
    }
  }

  if (ln == 0) out[j] = hmax;
}

extern "C" void kernel_launch(void* const* d_in, const int* in_sizes, int n_in,
                              void* d_out, int out_size, void* d_ws, size_t ws_size,
                              hipStream_t stream) {
  const float* inputs = (const float*)d_in[0];
  const float* Wx  = (const float*)d_in[1];
  const float* bx  = (const float*)d_in[2];
  const float* Wh  = (const float*)d_in[3];
  const float* bh  = (const float*)d_in[4];
  const float* Wum = (const float*)d_in[5];
  const float* bum = (const float*)d_in[6];
  const float* pic = (const float*)d_in[7];
  const float* pfc = (const float*)d_in[8];
  const float* poc = (const float*)d_in[9];
  const float* pzc = (const float*)d_in[10];
  float* out = (float*)d_out;

  // ws: Gx (2048*5120 f32) | h_pub (2*PUBI ints) | v_pub (2*PUBI ints)
  float* Gx = (float*)d_ws;
  int* h_pub = (int*)(Gx + (size_t)NNODE * GX_COLS);
  int* v_pub = h_pub + 2 * PUBI;

  init_ctrl<<<1, 256, 0, stream>>>(h_pub, v_pub);
  gemm_gx<<<dim3(GX_COLS / 128, NNODE / 128), 256, 0, stream>>>(inputs, Wx, bx, Gx);
  scan_kernel<<<NWG, WGT, 0, stream>>>(Wh, bh, Wum, bum, pic, pfc, poc, pzc,
                                       Gx, h_pub, v_pub, out);
}